// Round 9
// baseline (1030.170 us; speedup 1.0000x reference)
//
#include <hip/hip_runtime.h>
#include <hip/hip_bf16.h>

#define IN_FEATS 768
#define PART_CHUNK 4096
#define SRC_BITS 17
#define SRC_MASK 0x1FFFF

typedef __attribute__((ext_vector_type(8))) short short8v;
typedef __attribute__((ext_vector_type(4))) float f32x4;

__device__ __forceinline__ unsigned short f2bf(float f) {
    union { float f; unsigned int u; } c; c.f = f;
    unsigned int r = (c.u + 0x7FFFu + ((c.u >> 16) & 1u)) >> 16;  // RNE
    return (unsigned short)r;
}
__device__ __forceinline__ float bflo(unsigned int v) {
    union { unsigned int u; float f; } c; c.u = v << 16; return c.f;
}
__device__ __forceinline__ float bfhi(unsigned int v) {
    union { unsigned int u; float f; } c; c.u = v & 0xFFFF0000u; return c.f;
}
__device__ __forceinline__ short8v pack8(float4 p, float4 q) {
    short8v r;
    r[0] = (short)f2bf(p.x); r[1] = (short)f2bf(p.y);
    r[2] = (short)f2bf(p.z); r[3] = (short)f2bf(p.w);
    r[4] = (short)f2bf(q.x); r[5] = (short)f2bf(q.y);
    r[6] = (short)f2bf(q.z); r[7] = (short)f2bf(q.w);
    return r;
}

// ---------------------------------------------------------------------------
// Kernel 1 v3: fused layer-1 linear via bf16 MFMA.
// Linear [2][64][64] LDS (32 KB total) + XOR swizzle elem ^= (row&7)<<3:
// write side 8 lanes/bank-group (2-way = free), read side 2 lanes/bank-group.
// Fixes the 1.8e7 SQ_LDS_BANK_CONFLICT measured on the 144B-stride layout.
// ---------------------------------------------------------------------------
__global__ __launch_bounds__(256) void gemm1_kernel(
    const float* __restrict__ x,
    const float* __restrict__ Wn,
    const float* __restrict__ Ws,
    const float* __restrict__ b1,
    unsigned short* __restrict__ hn1b,   // [N,32] bf16 bits
    float* __restrict__ hs1,             // [N,32]
    int N)
{
    __shared__ unsigned short As[2][64][64];
    __shared__ unsigned short Bs[2][64][64];

    const int tid  = threadIdx.x;
    const int lrow = tid >> 2;          // staging row 0..63
    const int lk16 = (tid & 3) * 16;    // staging k-offset 0,16,32,48
    const int row0 = blockIdx.x * 64;

    const int  grow   = row0 + lrow;
    const bool rvalid = (grow < N);
    const float* xrow = x + (size_t)(rvalid ? grow : (N - 1)) * IN_FEATS;
    const float* wrow = (lrow < 32) ? (Wn + (size_t)lrow * IN_FEATS)
                                    : (Ws + (size_t)(lrow - 32) * IN_FEATS);

    const int w    = tid >> 6;          // wave 0..3
    const int l    = tid & 63;
    const int lr16 = l & 15;
    const int lk   = (l >> 4) * 8;      // 0,8,16,24

    const int sws  = (lrow & 7) << 3;           // write-side swizzle
    const int ra   = w * 16 + lr16;
    const int swa  = (ra & 7) << 3;             // A read-side swizzle

    f32x4 acc[4];
#pragma unroll
    for (int ct = 0; ct < 4; ++ct) acc[ct] = (f32x4){0.f, 0.f, 0.f, 0.f};

    float4 a0, a1, a2, a3, w0, w1, w2, w3;
    a0 = *(const float4*)(xrow + lk16 + 0);
    a1 = *(const float4*)(xrow + lk16 + 4);
    a2 = *(const float4*)(xrow + lk16 + 8);
    a3 = *(const float4*)(xrow + lk16 + 12);
    w0 = *(const float4*)(wrow + lk16 + 0);
    w1 = *(const float4*)(wrow + lk16 + 4);
    w2 = *(const float4*)(wrow + lk16 + 8);
    w3 = *(const float4*)(wrow + lk16 + 12);

    const int NSTEP = IN_FEATS / 64;    // 12
    for (int step = 0; step < NSTEP; ++step) {
        const int buf = step & 1;
        *(short8v*)&As[buf][lrow][(lk16 + 0) ^ sws] = pack8(a0, a1);
        *(short8v*)&As[buf][lrow][(lk16 + 8) ^ sws] = pack8(a2, a3);
        *(short8v*)&Bs[buf][lrow][(lk16 + 0) ^ sws] = pack8(w0, w1);
        *(short8v*)&Bs[buf][lrow][(lk16 + 8) ^ sws] = pack8(w2, w3);
        __syncthreads();

        if (step + 1 < NSTEP) {
            const int k0 = (step + 1) * 64;
            a0 = *(const float4*)(xrow + k0 + lk16 + 0);
            a1 = *(const float4*)(xrow + k0 + lk16 + 4);
            a2 = *(const float4*)(xrow + k0 + lk16 + 8);
            a3 = *(const float4*)(xrow + k0 + lk16 + 12);
            w0 = *(const float4*)(wrow + k0 + lk16 + 0);
            w1 = *(const float4*)(wrow + k0 + lk16 + 4);
            w2 = *(const float4*)(wrow + k0 + lk16 + 8);
            w3 = *(const float4*)(wrow + k0 + lk16 + 12);
        }

        short8v af0 = *(const short8v*)&As[buf][ra][(lk +  0) ^ swa];
        short8v af1 = *(const short8v*)&As[buf][ra][(lk + 32) ^ swa];
#pragma unroll
        for (int ct = 0; ct < 4; ++ct) {
            const int rb  = ct * 16 + lr16;
            const int swb = (rb & 7) << 3;
            short8v bf0 = *(const short8v*)&Bs[buf][rb][(lk +  0) ^ swb];
            acc[ct] = __builtin_amdgcn_mfma_f32_16x16x32_bf16(af0, bf0, acc[ct], 0, 0, 0);
        }
#pragma unroll
        for (int ct = 0; ct < 4; ++ct) {
            const int rb  = ct * 16 + lr16;
            const int swb = (rb & 7) << 3;
            short8v bf1 = *(const short8v*)&Bs[buf][rb][(lk + 32) ^ swb];
            acc[ct] = __builtin_amdgcn_mfma_f32_16x16x32_bf16(af1, bf1, acc[ct], 0, 0, 0);
        }
    }

    // epilogue: D layout col=lane&15, row=(lane>>4)*4+reg
    const int rbase = row0 + w * 16 + (l >> 4) * 4;
#pragma unroll
    for (int ct = 0; ct < 4; ++ct) {
        const int ncol = ct * 16 + lr16;
        if (ncol < 32) {
#pragma unroll
            for (int j = 0; j < 4; ++j) {
                const int r = rbase + j;
                if (r < N) hn1b[(size_t)r * 32 + ncol] = f2bf(acc[ct][j]);
            }
        } else {
            const int c = ncol - 32;
            const float bias = b1[c];
#pragma unroll
            for (int j = 0; j < 4; ++j) {
                const int r = rbase + j;
                if (r < N) hs1[(size_t)r * 32 + c] = acc[ct][j] + bias;
            }
        }
    }
}

// ---------------------------------------------------------------------------
// Bucketed edge partition with STATIC per-bucket capacity CAP (= 2x mean
// bucket size -> overflow probability ~0; clamp guard keeps writes in-bounds).
// Replaces hist + scan + finalize: bstart[b] = b*CAP, count in bcursor[b].
// ---------------------------------------------------------------------------
__global__ __launch_bounds__(512) void init_cursor_kernel(
    int* __restrict__ bcursor, int NB, int CAP)
{
    const int t = threadIdx.x;
    if (t < NB) bcursor[t] = t * CAP;
}

__global__ __launch_bounds__(256) void partition_kernel(
    const int* __restrict__ src, const int* __restrict__ dst,
    int* __restrict__ bcursor, unsigned int* __restrict__ packed,
    int NB, int E, int CAP)
{
    __shared__ int hcnt[512];
    __shared__ int hbase[512];
    const int t = threadIdx.x;
    for (int i = t; i < NB; i += 256) hcnt[i] = 0;
    __syncthreads();

    const int start = blockIdx.x * PART_CHUNK;
    const int end   = min(start + PART_CHUNK, E);
    const int vend  = start + ((end - start) & ~3);   // full-quad region

    // pass 1: per-block histogram (int4 loads)
    for (int i = start + t * 4; i + 3 < end; i += 1024) {
        const int4 d4 = *(const int4*)&dst[i];
        atomicAdd(&hcnt[d4.x >> 8], 1);
        atomicAdd(&hcnt[d4.y >> 8], 1);
        atomicAdd(&hcnt[d4.z >> 8], 1);
        atomicAdd(&hcnt[d4.w >> 8], 1);
    }
    for (int i = vend + t; i < end; i += 256)
        atomicAdd(&hcnt[dst[i] >> 8], 1);
    __syncthreads();

    // reserve contiguous runs (one global atomic per touched bucket)
    for (int i = t; i < NB; i += 256) {
        const int c = hcnt[i];
        hbase[i] = c ? atomicAdd(&bcursor[i], c) : 0;
        hcnt[i] = 0;   // reuse as local cursor
    }
    __syncthreads();

    // pass 2: packed writes ((dst&255)<<17 | src) into the runs
    const int cap_all = NB * CAP;
    for (int i = start + t * 4; i + 3 < end; i += 1024) {
        const int4 d4 = *(const int4*)&dst[i];
        const int4 s4 = *(const int4*)&src[i];
        {
            const int b = d4.x >> 8;
            const int p = hbase[b] + atomicAdd(&hcnt[b], 1);
            if (p < cap_all) packed[p] = ((unsigned int)(d4.x & 255) << SRC_BITS) | (unsigned int)s4.x;
        }
        {
            const int b = d4.y >> 8;
            const int p = hbase[b] + atomicAdd(&hcnt[b], 1);
            if (p < cap_all) packed[p] = ((unsigned int)(d4.y & 255) << SRC_BITS) | (unsigned int)s4.y;
        }
        {
            const int b = d4.z >> 8;
            const int p = hbase[b] + atomicAdd(&hcnt[b], 1);
            if (p < cap_all) packed[p] = ((unsigned int)(d4.z & 255) << SRC_BITS) | (unsigned int)s4.z;
        }
        {
            const int b = d4.w >> 8;
            const int p = hbase[b] + atomicAdd(&hcnt[b], 1);
            if (p < cap_all) packed[p] = ((unsigned int)(d4.w & 255) << SRC_BITS) | (unsigned int)s4.w;
        }
    }
    for (int i = vend + t; i < end; i += 256) {
        const int d = dst[i];
        const int b = d >> 8;
        const int p = hbase[b] + atomicAdd(&hcnt[b], 1);
        if (p < cap_all) packed[p] = ((unsigned int)(d & 255) << SRC_BITS) | (unsigned int)src[i];
    }
}

// ---------------------------------------------------------------------------
// agg1 edge-centric: one block per 256-node bucket, LDS fp32 accumulators.
// Then finish in-block: h = relu(hs1 + acc/deg); hn2b = bf16(h@Wn2.T);
// hs2 = h@Ws2.T + b2. No CSR, no edge_src, no finalize kernel.
// ---------------------------------------------------------------------------
__global__ __launch_bounds__(1024) void agg1_fused_kernel(
    const unsigned short* __restrict__ hn1b, const float* __restrict__ hs1,
    const int* __restrict__ bcursor, const unsigned int* __restrict__ packed,
    const float* __restrict__ Wn2, const float* __restrict__ Ws2,
    const float* __restrict__ b2,
    unsigned short* __restrict__ hn2b, float* __restrict__ hs2,
    float* __restrict__ degf, int N, int CAP)
{
    __shared__ float accf[256][32];   // 32 KB accumulator (becomes h in place)
    __shared__ float degs[256];
    __shared__ float w2[16][33];
    __shared__ float bb[8];

    const int tid = threadIdx.x;
    const int b   = blockIdx.x;
    const int n0  = b << 8;
    const int nn  = min(256, N - n0);

    if (tid < 256) {
        w2[tid >> 5][tid & 31]       = Wn2[tid];
        w2[8 + (tid >> 5)][tid & 31] = Ws2[tid];
        if (tid < 8) bb[tid] = b2[tid];
        degs[tid] = 0.0f;
    }
    for (int i = tid; i < 256 * 32; i += 1024) ((float*)accf)[i] = 0.0f;
    __syncthreads();

    const unsigned int* hn1u = (const unsigned int*)hn1b;
    const int grp  = tid >> 4;       // 64 edges in flight per iteration
    const int ln   = tid & 15;
    const int base = b * CAP;
    const int endp = min(bcursor[b], base + CAP);

    for (int e = base + grp; e < endp; e += 64) {
        const unsigned int v = packed[e];
        const int d = (int)(v >> SRC_BITS);
        const int s = (int)(v & SRC_MASK);
        const unsigned int u = hn1u[(size_t)s * 16 + ln];
        atomicAdd(&accf[d][2 * ln + 0], bflo(u));
        atomicAdd(&accf[d][2 * ln + 1], bfhi(u));
        if (ln == 0) atomicAdd(&degs[d], 1.0f);
    }
    __syncthreads();

    // finish layer 1 in place: h = relu(hs1 + acc/deg)
    for (int idx = tid; idx < nn * 32; idx += 1024) {
        const int n = idx >> 5, k = idx & 31;
        const float dg  = degs[n];
        const float inv = 1.0f / fmaxf(dg, 1.0f);
        accf[n][k] = fmaxf(hs1[(size_t)(n0 + n) * 32 + k] + accf[n][k] * inv, 0.0f);
        if (k == 0) degf[n0 + n] = dg;
    }
    __syncthreads();

    // layer-2 linears: 16 outputs per node
    for (int idx = tid; idx < nn * 16; idx += 1024) {
        const int n = idx >> 4, o = idx & 15;
        const float* hv = accf[n];
        const float* wr = w2[o];
        float acc = 0.0f;
#pragma unroll
        for (int k = 0; k < 32; ++k) acc += wr[k] * hv[k];
        if (o < 8) hn2b[(size_t)(n0 + n) * 8 + o] = f2bf(acc);
        else       hs2[(size_t)(n0 + n) * 8 + (o - 8)] = acc + bb[o - 8];
    }
}

// ---------------------------------------------------------------------------
// agg2 edge-centric: one block per bucket, LDS accumulators, writes d_out.
// ---------------------------------------------------------------------------
__global__ __launch_bounds__(1024) void agg2_fused_kernel(
    const unsigned short* __restrict__ hn2b, const float* __restrict__ hs2,
    const float* __restrict__ degf,
    const int* __restrict__ bcursor, const unsigned int* __restrict__ packed,
    float* __restrict__ out, int N, int CAP)
{
    __shared__ float acc2[256][8];    // 8 KB

    const int tid = threadIdx.x;
    const int b   = blockIdx.x;
    const int n0  = b << 8;
    const int nn  = min(256, N - n0);

    for (int i = tid; i < 256 * 8; i += 1024) ((float*)acc2)[i] = 0.0f;
    __syncthreads();

    const unsigned int* hn2u = (const unsigned int*)hn2b;
    const int grp  = tid >> 2;       // 256 edges in flight per iteration
    const int q    = tid & 3;
    const int base = b * CAP;
    const int endp = min(bcursor[b], base + CAP);

    for (int e = base + grp; e < endp; e += 256) {
        const unsigned int v = packed[e];
        const int d = (int)(v >> SRC_BITS);
        const int s = (int)(v & SRC_MASK);
        const unsigned int u = hn2u[(size_t)s * 4 + q];
        atomicAdd(&acc2[d][2 * q + 0], bflo(u));
        atomicAdd(&acc2[d][2 * q + 1], bfhi(u));
    }
    __syncthreads();

    for (int idx = tid; idx < nn * 8; idx += 1024) {
        const int n = idx >> 3, j = idx & 7;
        const float inv = 1.0f / fmaxf(degf[n0 + n], 1.0f);
        out[(size_t)(n0 + n) * 8 + j] = hs2[(size_t)(n0 + n) * 8 + j] + acc2[n][j] * inv;
    }
}

extern "C" void kernel_launch(void* const* d_in, const int* in_sizes, int n_in,
                              void* d_out, int out_size, void* d_ws, size_t ws_size,
                              hipStream_t stream)
{
    const float* feats = (const float*)d_in[0];
    const int*   src   = (const int*)d_in[1];
    const int*   dst   = (const int*)d_in[2];
    const float* Ws1   = (const float*)d_in[3];
    const float* Wn1   = (const float*)d_in[4];
    const float* b1    = (const float*)d_in[5];
    const float* Ws2   = (const float*)d_in[6];
    const float* Wn2   = (const float*)d_in[7];
    const float* b2    = (const float*)d_in[8];
    float* out = (float*)d_out;

    const int N  = in_sizes[0] / IN_FEATS;   // 100000
    const int E  = in_sizes[1];              // 3200000
    const int NB = (N + 255) >> 8;           // 391 buckets of 256 nodes
    const int CAP = (int)((((2LL * E) / NB) + 255) & ~255LL);   // 16384: 2x mean

    // Workspace layout
    char* ws = (char*)d_ws;
    const size_t N32 = (size_t)N * 32;
    const size_t N8  = (size_t)N * 8;
    unsigned short* hn1b = (unsigned short*)ws;            // [N,32] bf16
    ws += ((N32 * 2 + 255) / 256) * 256;
    float* hs1 = (float*)ws;                               // [N,32] f32
    ws += ((N32 * 4 + 255) / 256) * 256;
    unsigned short* hn2b = (unsigned short*)ws;            // [N,8] bf16
    ws += ((N8 * 2 + 255) / 256) * 256;
    float* hs2 = (float*)ws;                               // [N,8] f32
    ws += ((N8 * 4 + 255) / 256) * 256;
    float* degf = (float*)ws;                              // [N]
    ws += (((size_t)N * 4 + 255) / 256) * 256;
    int* bcursor = (int*)ws;                               // [512]
    ws += 512 * 4;
    unsigned int* packed = (unsigned int*)ws;              // [NB*CAP]

    const int nbPart = (E + PART_CHUNK - 1) / PART_CHUNK;

    // --- bucketed edge partition (static capacities; no hist/scan/finalize) ---
    init_cursor_kernel<<<1, 512, 0, stream>>>(bcursor, NB, CAP);
    partition_kernel<<<nbPart, 256, 0, stream>>>(src, dst, bcursor, packed,
                                                 NB, E, CAP);

    // --- layer-1 fused GEMM (bf16 MFMA, swizzled LDS) ---
    gemm1_kernel<<<(N + 63) / 64, 256, 0, stream>>>(feats, Wn1, Ws1, b1,
                                                    hn1b, hs1, N);

    // --- layer-1 aggregation (edge-centric LDS acc) + finish + layer-2 linear ---
    agg1_fused_kernel<<<NB, 1024, 0, stream>>>(
        hn1b, hs1, bcursor, packed, Wn2, Ws2, b2, hn2b, hs2, degf, N, CAP);

    // --- layer-2 aggregation (edge-centric LDS acc) + final combine ---
    agg2_fused_kernel<<<NB, 1024, 0, stream>>>(
        hn2b, hs2, degf, bcursor, packed, out, N, CAP);
}

// Round 10
// 255.627 us; speedup vs baseline: 4.0300x; 4.0300x over previous
//
#include <hip/hip_runtime.h>
#include <hip/hip_bf16.h>

#define IN_FEATS 768
#define PART_CHUNK 4096
#define SRC_BITS 17
#define SRC_MASK 0x1FFFF

typedef __attribute__((ext_vector_type(8))) short short8v;
typedef __attribute__((ext_vector_type(4))) float f32x4;

__device__ __forceinline__ unsigned short f2bf(float f) {
    union { float f; unsigned int u; } c; c.f = f;
    unsigned int r = (c.u + 0x7FFFu + ((c.u >> 16) & 1u)) >> 16;  // RNE
    return (unsigned short)r;
}
__device__ __forceinline__ float bflo(unsigned int v) {
    union { unsigned int u; float f; } c; c.u = v << 16; return c.f;
}
__device__ __forceinline__ float bfhi(unsigned int v) {
    union { unsigned int u; float f; } c; c.u = v & 0xFFFF0000u; return c.f;
}
__device__ __forceinline__ short8v pack8(float4 p, float4 q) {
    short8v r;
    r[0] = (short)f2bf(p.x); r[1] = (short)f2bf(p.y);
    r[2] = (short)f2bf(p.z); r[3] = (short)f2bf(p.w);
    r[4] = (short)f2bf(q.x); r[5] = (short)f2bf(q.y);
    r[6] = (short)f2bf(q.z); r[7] = (short)f2bf(q.w);
    return r;
}

// ---------------------------------------------------------------------------
// Kernel 1 v3 (validated in round 9): fused layer-1 linear via bf16 MFMA.
// Linear [2][64][64] LDS (32 KB) + XOR swizzle elem ^= (row&7)<<3.
// ---------------------------------------------------------------------------
__global__ __launch_bounds__(256) void gemm1_kernel(
    const float* __restrict__ x,
    const float* __restrict__ Wn,
    const float* __restrict__ Ws,
    const float* __restrict__ b1,
    unsigned short* __restrict__ hn1b,   // [N,32] bf16 bits
    float* __restrict__ hs1,             // [N,32]
    int N)
{
    __shared__ unsigned short As[2][64][64];
    __shared__ unsigned short Bs[2][64][64];

    const int tid  = threadIdx.x;
    const int lrow = tid >> 2;          // staging row 0..63
    const int lk16 = (tid & 3) * 16;    // staging k-offset 0,16,32,48
    const int row0 = blockIdx.x * 64;

    const int  grow   = row0 + lrow;
    const bool rvalid = (grow < N);
    const float* xrow = x + (size_t)(rvalid ? grow : (N - 1)) * IN_FEATS;
    const float* wrow = (lrow < 32) ? (Wn + (size_t)lrow * IN_FEATS)
                                    : (Ws + (size_t)(lrow - 32) * IN_FEATS);

    const int w    = tid >> 6;          // wave 0..3
    const int l    = tid & 63;
    const int lr16 = l & 15;
    const int lk   = (l >> 4) * 8;      // 0,8,16,24

    const int sws  = (lrow & 7) << 3;           // write-side swizzle
    const int ra   = w * 16 + lr16;
    const int swa  = (ra & 7) << 3;             // A read-side swizzle

    f32x4 acc[4];
#pragma unroll
    for (int ct = 0; ct < 4; ++ct) acc[ct] = (f32x4){0.f, 0.f, 0.f, 0.f};

    float4 a0, a1, a2, a3, w0, w1, w2, w3;
    a0 = *(const float4*)(xrow + lk16 + 0);
    a1 = *(const float4*)(xrow + lk16 + 4);
    a2 = *(const float4*)(xrow + lk16 + 8);
    a3 = *(const float4*)(xrow + lk16 + 12);
    w0 = *(const float4*)(wrow + lk16 + 0);
    w1 = *(const float4*)(wrow + lk16 + 4);
    w2 = *(const float4*)(wrow + lk16 + 8);
    w3 = *(const float4*)(wrow + lk16 + 12);

    const int NSTEP = IN_FEATS / 64;    // 12
    for (int step = 0; step < NSTEP; ++step) {
        const int buf = step & 1;
        *(short8v*)&As[buf][lrow][(lk16 + 0) ^ sws] = pack8(a0, a1);
        *(short8v*)&As[buf][lrow][(lk16 + 8) ^ sws] = pack8(a2, a3);
        *(short8v*)&Bs[buf][lrow][(lk16 + 0) ^ sws] = pack8(w0, w1);
        *(short8v*)&Bs[buf][lrow][(lk16 + 8) ^ sws] = pack8(w2, w3);
        __syncthreads();

        if (step + 1 < NSTEP) {
            const int k0 = (step + 1) * 64;
            a0 = *(const float4*)(xrow + k0 + lk16 + 0);
            a1 = *(const float4*)(xrow + k0 + lk16 + 4);
            a2 = *(const float4*)(xrow + k0 + lk16 + 8);
            a3 = *(const float4*)(xrow + k0 + lk16 + 12);
            w0 = *(const float4*)(wrow + k0 + lk16 + 0);
            w1 = *(const float4*)(wrow + k0 + lk16 + 4);
            w2 = *(const float4*)(wrow + k0 + lk16 + 8);
            w3 = *(const float4*)(wrow + k0 + lk16 + 12);
        }

        short8v af0 = *(const short8v*)&As[buf][ra][(lk +  0) ^ swa];
        short8v af1 = *(const short8v*)&As[buf][ra][(lk + 32) ^ swa];
#pragma unroll
        for (int ct = 0; ct < 4; ++ct) {
            const int rb  = ct * 16 + lr16;
            const int swb = (rb & 7) << 3;
            short8v bf0 = *(const short8v*)&Bs[buf][rb][(lk +  0) ^ swb];
            acc[ct] = __builtin_amdgcn_mfma_f32_16x16x32_bf16(af0, bf0, acc[ct], 0, 0, 0);
        }
#pragma unroll
        for (int ct = 0; ct < 4; ++ct) {
            const int rb  = ct * 16 + lr16;
            const int swb = (rb & 7) << 3;
            short8v bf1 = *(const short8v*)&Bs[buf][rb][(lk + 32) ^ swb];
            acc[ct] = __builtin_amdgcn_mfma_f32_16x16x32_bf16(af1, bf1, acc[ct], 0, 0, 0);
        }
    }

    // epilogue: D layout col=lane&15, row=(lane>>4)*4+reg
    const int rbase = row0 + w * 16 + (l >> 4) * 4;
#pragma unroll
    for (int ct = 0; ct < 4; ++ct) {
        const int ncol = ct * 16 + lr16;
        if (ncol < 32) {
#pragma unroll
            for (int j = 0; j < 4; ++j) {
                const int r = rbase + j;
                if (r < N) hn1b[(size_t)r * 32 + ncol] = f2bf(acc[ct][j]);
            }
        } else {
            const int c = ncol - 32;
            const float bias = b1[c];
#pragma unroll
            for (int j = 0; j < 4; ++j) {
                const int r = rbase + j;
                if (r < N) hs1[(size_t)r * 32 + c] = acc[ct][j] + bias;
            }
        }
    }
}

// ---------------------------------------------------------------------------
// Bucketed edge partition with STATIC per-bucket capacity (CAP = 2x mean
// = mean + 91 sigma -> overflow impossible; per-bucket clamp guards anyway).
// Replaces zero/hist/scan: bucket b owns packed[b*CAP .. b*CAP+count).
// ---------------------------------------------------------------------------
__global__ __launch_bounds__(512) void init_cursor_kernel(
    int* __restrict__ bcursor, int NB, int CAP)
{
    const int t = threadIdx.x;
    if (t < NB) bcursor[t] = t * CAP;
}

__global__ __launch_bounds__(256) void partition_kernel(
    const int* __restrict__ src, const int* __restrict__ dst,
    int* __restrict__ bcursor, unsigned int* __restrict__ packed,
    int NB, int E, int CAP)
{
    __shared__ int hcnt[512];
    __shared__ int hbase[512];
    const int t = threadIdx.x;
    for (int i = t; i < NB; i += 256) hcnt[i] = 0;
    __syncthreads();

    const int start = blockIdx.x * PART_CHUNK;
    const int end   = min(start + PART_CHUNK, E);
    const int vend  = start + ((end - start) & ~3);   // full-quad region

    // pass 1: per-block histogram (int4 loads)
    for (int i = start + t * 4; i + 3 < end; i += 1024) {
        const int4 d4 = *(const int4*)&dst[i];
        atomicAdd(&hcnt[d4.x >> 8], 1);
        atomicAdd(&hcnt[d4.y >> 8], 1);
        atomicAdd(&hcnt[d4.z >> 8], 1);
        atomicAdd(&hcnt[d4.w >> 8], 1);
    }
    for (int i = vend + t; i < end; i += 256)
        atomicAdd(&hcnt[dst[i] >> 8], 1);
    __syncthreads();

    // reserve contiguous runs (one global atomic per touched bucket)
    for (int i = t; i < NB; i += 256) {
        const int c = hcnt[i];
        hbase[i] = c ? atomicAdd(&bcursor[i], c) : 0;
        hcnt[i] = 0;   // reuse as local cursor
    }
    __syncthreads();

    // pass 2: packed writes ((dst&255)<<17 | src) into the runs
    for (int i = start + t * 4; i + 3 < end; i += 1024) {
        const int4 d4 = *(const int4*)&dst[i];
        const int4 s4 = *(const int4*)&src[i];
        {
            const int b = d4.x >> 8;
            const int p = hbase[b] + atomicAdd(&hcnt[b], 1);
            if (p < (b + 1) * CAP) packed[p] = ((unsigned int)(d4.x & 255) << SRC_BITS) | (unsigned int)s4.x;
        }
        {
            const int b = d4.y >> 8;
            const int p = hbase[b] + atomicAdd(&hcnt[b], 1);
            if (p < (b + 1) * CAP) packed[p] = ((unsigned int)(d4.y & 255) << SRC_BITS) | (unsigned int)s4.y;
        }
        {
            const int b = d4.z >> 8;
            const int p = hbase[b] + atomicAdd(&hcnt[b], 1);
            if (p < (b + 1) * CAP) packed[p] = ((unsigned int)(d4.z & 255) << SRC_BITS) | (unsigned int)s4.z;
        }
        {
            const int b = d4.w >> 8;
            const int p = hbase[b] + atomicAdd(&hcnt[b], 1);
            if (p < (b + 1) * CAP) packed[p] = ((unsigned int)(d4.w & 255) << SRC_BITS) | (unsigned int)s4.w;
        }
    }
    for (int i = vend + t; i < end; i += 256) {
        const int d = dst[i];
        const int b = d >> 8;
        const int p = hbase[b] + atomicAdd(&hcnt[b], 1);
        if (p < (b + 1) * CAP) packed[p] = ((unsigned int)(d & 255) << SRC_BITS) | (unsigned int)src[i];
    }
}

// ---------------------------------------------------------------------------
// Per-bucket CSR finalize (padded coordinates — no global scan needed):
// rowstart[n] = b*CAP + excl, rowcnt[n] = count; scatter src into edge_src
// within the bucket's window (single-XCD L2 locality).
// ---------------------------------------------------------------------------
__global__ __launch_bounds__(1024) void csr_finalize_kernel(
    const unsigned int* __restrict__ packed, const int* __restrict__ bcursor,
    int* __restrict__ rowstart, int* __restrict__ rowcnt,
    int* __restrict__ edge_src, int N, int CAP)
{
    __shared__ int cnt[256];
    __shared__ int sdata[256];
    __shared__ int cur[256];
    const int b = blockIdx.x;
    const int t = threadIdx.x;
    const int base = b * CAP;
    const int endp = min(bcursor[b], base + CAP);

    if (t < 256) cnt[t] = 0;
    __syncthreads();
    for (int i = base + t; i < endp; i += 1024)
        atomicAdd(&cnt[packed[i] >> SRC_BITS], 1);
    __syncthreads();

    if (t < 256) sdata[t] = cnt[t];
    __syncthreads();
    for (int off = 1; off < 256; off <<= 1) {
        const int add = (t < 256 && t >= off) ? sdata[t - off] : 0;
        __syncthreads();
        if (t < 256) sdata[t] += add;
        __syncthreads();
    }
    if (t < 256) {
        const int excl = (t > 0) ? sdata[t - 1] : 0;
        const int n = (b << 8) + t;
        if (n < N) {
            rowstart[n] = base + excl;
            rowcnt[n]   = cnt[t];
        }
        cur[t] = base + excl;
    }
    __syncthreads();

    for (int i = base + t; i < endp; i += 1024) {
        const unsigned int v = packed[i];
        const int pos = atomicAdd(&cur[v >> SRC_BITS], 1);
        edge_src[pos] = (int)(v & SRC_MASK);
    }
}

// ---------------------------------------------------------------------------
// agg1 fused, node-centric (restored): 16 nodes/block, 16 lanes/node,
// bf16x2 gathers; rowstart/rowcnt instead of rowstart[n+1].
// ---------------------------------------------------------------------------
__global__ __launch_bounds__(256) void agg1_fused_kernel(
    const unsigned short* __restrict__ hn1b, const float* __restrict__ hs1,
    const int* __restrict__ rowstart, const int* __restrict__ rowcnt,
    const int* __restrict__ edge_src,
    const float* __restrict__ Wn2, const float* __restrict__ Ws2,
    const float* __restrict__ b2,
    unsigned short* __restrict__ hn2b, float* __restrict__ hs2, int N)
{
    __shared__ float w2[16][33];
    __shared__ float bb[8];
    __shared__ float hsm[16][33];

    const int tid = threadIdx.x;
    const int g   = tid >> 4;
    const int ln  = tid & 15;

    w2[tid >> 5][tid & 31]       = Wn2[tid];
    w2[8 + (tid >> 5)][tid & 31] = Ws2[tid];
    if (tid < 8) bb[tid] = b2[tid];

    const unsigned int* hn1u = (const unsigned int*)hn1b;

    const int n = blockIdx.x * 16 + g;
    float sx = 0.f, sy = 0.f;
    int degi = 0;
    if (n < N) {
        const int rs = rowstart[n];
        degi = rowcnt[n];
        const int re = rs + degi;
        int e = rs;
        for (; e + 8 <= re; e += 8) {
            const int s0 = edge_src[e + 0];
            const int s1 = edge_src[e + 1];
            const int s2 = edge_src[e + 2];
            const int s3 = edge_src[e + 3];
            const int s4 = edge_src[e + 4];
            const int s5 = edge_src[e + 5];
            const int s6 = edge_src[e + 6];
            const int s7 = edge_src[e + 7];
            const unsigned int v0 = hn1u[(size_t)s0 * 16 + ln];
            const unsigned int v1 = hn1u[(size_t)s1 * 16 + ln];
            const unsigned int v2 = hn1u[(size_t)s2 * 16 + ln];
            const unsigned int v3 = hn1u[(size_t)s3 * 16 + ln];
            const unsigned int v4 = hn1u[(size_t)s4 * 16 + ln];
            const unsigned int v5 = hn1u[(size_t)s5 * 16 + ln];
            const unsigned int v6 = hn1u[(size_t)s6 * 16 + ln];
            const unsigned int v7 = hn1u[(size_t)s7 * 16 + ln];
            sx += ((bflo(v0) + bflo(v1)) + (bflo(v2) + bflo(v3)))
                + ((bflo(v4) + bflo(v5)) + (bflo(v6) + bflo(v7)));
            sy += ((bfhi(v0) + bfhi(v1)) + (bfhi(v2) + bfhi(v3)))
                + ((bfhi(v4) + bfhi(v5)) + (bfhi(v6) + bfhi(v7)));
        }
        for (; e < re; ++e) {
            const unsigned int v = hn1u[(size_t)edge_src[e] * 16 + ln];
            sx += bflo(v); sy += bfhi(v);
        }
        const float inv = 1.0f / fmaxf((float)degi, 1.0f);
        const float2 hs = *(const float2*)(hs1 + (size_t)n * 32 + 2 * ln);
        hsm[g][2 * ln + 0] = fmaxf(hs.x + sx * inv, 0.0f);
        hsm[g][2 * ln + 1] = fmaxf(hs.y + sy * inv, 0.0f);
    }
    __syncthreads();

    if (n < N) {
        const float* wrow = w2[ln];
        const float* hv   = hsm[g];
        float acc = 0.0f;
#pragma unroll
        for (int k = 0; k < 32; ++k) acc += wrow[k] * hv[k];
        if (ln < 8) hn2b[(size_t)n * 8 + ln] = f2bf(acc);
        else        hs2[(size_t)n * 8 + (ln - 8)] = acc + bb[ln - 8];
    }
}

// ---------------------------------------------------------------------------
// agg2 fused, node-centric (restored): out = hs2 + mean(gather hn2b)
// ---------------------------------------------------------------------------
__global__ __launch_bounds__(256) void agg2_fused_kernel(
    const unsigned short* __restrict__ hn2b, const float* __restrict__ hs2,
    const int* __restrict__ rowstart, const int* __restrict__ rowcnt,
    const int* __restrict__ edge_src,
    float* __restrict__ out, int N)
{
    const int tid  = threadIdx.x;
    const int g    = tid >> 4;
    const int ln   = tid & 15;
    const int slot = ln >> 2;
    const int q    = ln & 3;

    const unsigned int* hn2u = (const unsigned int*)hn2b;

    const int n = blockIdx.x * 16 + g;
    float sx = 0.f, sy = 0.f;
    int degi = 0;
    if (n < N) {
        const int rs = rowstart[n];
        degi = rowcnt[n];
        const int re = rs + degi;
        for (int e = rs + slot; e < re; e += 4) {
            const unsigned int v = hn2u[(size_t)edge_src[e] * 4 + q];
            sx += bflo(v); sy += bfhi(v);
        }
    }
    sx += __shfl_xor(sx, 4, 64);  sy += __shfl_xor(sy, 4, 64);
    sx += __shfl_xor(sx, 8, 64);  sy += __shfl_xor(sy, 8, 64);

    if (n < N && slot == 0) {
        const float inv = 1.0f / fmaxf((float)degi, 1.0f);
        const float2 s = *(const float2*)(hs2 + (size_t)n * 8 + 2 * q);
        float2 o;
        o.x = s.x + sx * inv;
        o.y = s.y + sy * inv;
        *(float2*)(out + (size_t)n * 8 + 2 * q) = o;
    }
}

extern "C" void kernel_launch(void* const* d_in, const int* in_sizes, int n_in,
                              void* d_out, int out_size, void* d_ws, size_t ws_size,
                              hipStream_t stream)
{
    const float* feats = (const float*)d_in[0];
    const int*   src   = (const int*)d_in[1];
    const int*   dst   = (const int*)d_in[2];
    const float* Ws1   = (const float*)d_in[3];
    const float* Wn1   = (const float*)d_in[4];
    const float* b1    = (const float*)d_in[5];
    const float* Ws2   = (const float*)d_in[6];
    const float* Wn2   = (const float*)d_in[7];
    const float* b2    = (const float*)d_in[8];
    float* out = (float*)d_out;

    const int N  = in_sizes[0] / IN_FEATS;   // 100000
    const int E  = in_sizes[1];              // 3200000
    const int NB = (N + 255) >> 8;           // 391 buckets of 256 nodes
    const int CAP = (int)((((2LL * E) / NB) + 255) & ~255LL);   // 16384

    // Workspace layout
    char* ws = (char*)d_ws;
    const size_t N32 = (size_t)N * 32;
    const size_t N8  = (size_t)N * 8;
    unsigned short* hn1b = (unsigned short*)ws;            // [N,32] bf16
    ws += ((N32 * 2 + 255) / 256) * 256;
    float* hs1 = (float*)ws;                               // [N,32] f32
    ws += ((N32 * 4 + 255) / 256) * 256;
    unsigned short* hn2b = (unsigned short*)ws;            // [N,8] bf16
    ws += ((N8 * 2 + 255) / 256) * 256;
    float* hs2 = (float*)ws;                               // [N,8] f32
    ws += ((N8 * 4 + 255) / 256) * 256;
    int* rowstart = (int*)ws;                              // [N]
    ws += (((size_t)N * 4 + 255) / 256) * 256;
    int* rowcnt = (int*)ws;                                // [N]
    ws += (((size_t)N * 4 + 255) / 256) * 256;
    int* bcursor = (int*)ws;                               // [512]
    ws += 512 * 4;
    unsigned int* packed = (unsigned int*)ws;              // [NB*CAP]
    ws += (((size_t)NB * CAP * 4 + 255) / 256) * 256;
    int* edge_src = (int*)ws;                              // [NB*CAP]

    const int nbPart = (E + PART_CHUNK - 1) / PART_CHUNK;

    // --- CSR build: static-CAP partition + per-bucket finalize ---
    init_cursor_kernel<<<1, 512, 0, stream>>>(bcursor, NB, CAP);
    partition_kernel<<<nbPart, 256, 0, stream>>>(src, dst, bcursor, packed,
                                                 NB, E, CAP);
    csr_finalize_kernel<<<NB, 1024, 0, stream>>>(packed, bcursor, rowstart,
                                                 rowcnt, edge_src, N, CAP);

    // --- layer-1 fused GEMM (bf16 MFMA, swizzled LDS) ---
    gemm1_kernel<<<(N + 63) / 64, 256, 0, stream>>>(feats, Wn1, Ws1, b1,
                                                    hn1b, hs1, N);

    // --- layer-1 aggregation + finish + layer-2 linear (node-centric) ---
    agg1_fused_kernel<<<(N + 15) / 16, 256, 0, stream>>>(
        hn1b, hs1, rowstart, rowcnt, edge_src, Wn2, Ws2, b2, hn2b, hs2, N);

    // --- layer-2 aggregation + final combine (node-centric) ---
    agg2_fused_kernel<<<(N + 15) / 16, 256, 0, stream>>>(
        hn2b, hs2, rowstart, rowcnt, edge_src, out, N);
}